// Round 12
// baseline (94.812 us; speedup 1.0000x reference)
//
#include <hip/hip_runtime.h>
#include <hip/hip_bf16.h>
#include <cstdint>

#define KD 512
#define BM 128
#define NT 512
#define NSPLIT 63
#define NNODES 127
#define BH_OFF 32768       // B hi plane [64 rows][8 slots][16B] = 8 KB
#define BL_OFF 40960       // B lo plane = 8 KB; total LDS 48 KB -> 3 blocks/CU

typedef __attribute__((ext_vector_type(8))) short bf16x8;
typedef __attribute__((ext_vector_type(4))) float f32x4;

#define MFMA_B16(a, b, c) __builtin_amdgcn_mfma_f32_16x16x32_bf16(a, b, c, 0, 0, 0)
#define SCHED_FENCE() __builtin_amdgcn_sched_barrier(0)

static __device__ __forceinline__ unsigned short f2bf(float f) {
    return __builtin_bit_cast(unsigned short, __float2bfloat16(f));
}
static __device__ __forceinline__ float bf2f(unsigned short h) {
    return __builtin_bit_cast(float, (unsigned)h << 16);
}
static __device__ __forceinline__ unsigned pack2(float f0, float f1) {
    return (unsigned)f2bf(f0) | ((unsigned)f2bf(f1) << 16);
}

// 8 fp32 -> bf16 hi8 + residual lo8; named scalars only (stays in VGPRs)
static __device__ __forceinline__ void cvt8(f32x4 a, f32x4 b, bf16x8& hi, bf16x8& lo) {
    const unsigned short h0 = f2bf(a[0]), h1 = f2bf(a[1]), h2 = f2bf(a[2]), h3 = f2bf(a[3]);
    const unsigned short h4 = f2bf(b[0]), h5 = f2bf(b[1]), h6 = f2bf(b[2]), h7 = f2bf(b[3]);
    uint4 H = make_uint4((unsigned)h0 | ((unsigned)h1 << 16), (unsigned)h2 | ((unsigned)h3 << 16),
                         (unsigned)h4 | ((unsigned)h5 << 16), (unsigned)h6 | ((unsigned)h7 << 16));
    uint4 L = make_uint4(pack2(a[0] - bf2f(h0), a[1] - bf2f(h1)),
                         pack2(a[2] - bf2f(h2), a[3] - bf2f(h3)),
                         pack2(b[0] - bf2f(h4), b[1] - bf2f(h5)),
                         pack2(b[2] - bf2f(h6), b[3] - bf2f(h7)));
    hi = __builtin_bit_cast(bf16x8, H);
    lo = __builtin_bit_cast(bf16x8, L);
}

static __device__ __forceinline__ void gload_lds16(const void* g, void* l) {
    __builtin_amdgcn_global_load_lds(
        (const __attribute__((address_space(1))) unsigned int*)g,
        (__attribute__((address_space(3))) unsigned int*)l, 16, 0, 0);
}

template<int N> static __device__ __forceinline__ void vmwait() {
    if constexpr (N == 4)      asm volatile("s_waitcnt vmcnt(4)" ::: "memory");
    else if constexpr (N == 2) asm volatile("s_waitcnt vmcnt(2)" ::: "memory");
    else                       asm volatile("s_waitcnt vmcnt(0)" ::: "memory");
}

// DFS path-min; lane part16 stores clipped nodes [part16*8, part16*8+8)
template<int T>
static __device__ __forceinline__ void tree_walk16(float qt, const float* __restrict__ srow,
                                                   float* __restrict__ zrow, int part16) {
    const float s  = srow[T];
    const float ql = fminf(qt, s);
    const float qr = fminf(qt, -s);
    if (((2 * T + 1) >> 3) == part16) zrow[2 * T + 1] = fminf(fmaxf(ql, 0.f), 1.f);
    if (((2 * T + 2) >> 3) == part16) zrow[2 * T + 2] = fminf(fmaxf(qr, 0.f), 1.f);
    if constexpr (2 * T + 1 < NSPLIT) tree_walk16<2 * T + 1>(ql, srow, zrow, part16);
    if constexpr (2 * T + 2 < NSPLIT) tree_walk16<2 * T + 2>(qr, srow, zrow, part16);
}

// stage B chunk (64 rows x 64 k) bf16 hi/lo from regs; slot-swizzled b128 writes
static __device__ __forceinline__ void write_B(unsigned char* lds, int brow, int sl,
                                               bool bvalid, f32x4 b0, f32x4 b1) {
    if (!bvalid) { b0 = (f32x4)(0.f); b1 = (f32x4)(0.f); }
    bf16x8 hi, lo;
    cvt8(b0, b1, hi, lo);
    *reinterpret_cast<bf16x8*>(lds + BH_OFF + brow * 128 + sl * 16) = hi;
    *reinterpret_cast<bf16x8*>(lds + BL_OFF + brow * 128 + sl * 16) = lo;
}

// one 32-k tile. R7 queue discipline: bn waited only at coarse chunk boundaries
// (landed L2 loads), x retired by counted vmcnt that never drains younger loads.
// Hand-simulated queue, T=0..15: even T<=12 -> vmcnt(4); odd -> vmcnt(2);
// T=14 -> vmcnt(2); T=15 -> vmcnt(0).
template<int T>
static __device__ __forceinline__ void tiles(
        const float* xsrc, unsigned char* xw, unsigned char* lds,
        const float* ag, bool bvalid, int brow, int sl,
        int va_off, int fr, int g, f32x4 (&acc)[4], f32x4& bn0, f32x4& bn1) {
    if constexpr ((T & 1) == 0 && T > 0) {   // chunk boundary c = T/2
        SCHED_FENCE();
        __builtin_amdgcn_s_barrier();        // all waves done reading chunk c-1
        write_B(lds, brow, sl, bvalid, bn0, bn1);   // compiler waits bn only (landed)
        asm volatile("s_waitcnt lgkmcnt(0)" ::: "memory");
        __builtin_amdgcn_s_barrier();        // chunk c visible
        SCHED_FENCE();
        if constexpr (T / 2 + 1 < 8) {       // bn regs for chunk c+1 (L2-hot)
            if (bvalid) {
                bn0 = *reinterpret_cast<const f32x4*>(ag + (T / 2 + 1) * 64);
                bn1 = *reinterpret_cast<const f32x4*>(ag + (T / 2 + 1) * 64 + 4);
            }
        }
        SCHED_FENCE();
    }
    if constexpr (T + 1 < 16) {              // depth-1 x prefetch into other buffer
        unsigned char* nb = xw + ((T + 1) & 1) * 2048;
        gload_lds16(xsrc + (T + 1) * 32, nb);
        gload_lds16(xsrc + (T + 1) * 32 + 8 * KD, nb + 1024);
    }
    SCHED_FENCE();
    vmwait<((T & 1) == 0 && T <= 12) ? 4 : ((T == 15) ? 0 : 2)>();   // retire x_T
    SCHED_FENCE();

    const unsigned char* xbf = xw + (T & 1) * 2048;
    f32x4 va = *reinterpret_cast<const f32x4*>(xbf + va_off);
    f32x4 vb = *reinterpret_cast<const f32x4*>(xbf + (va_off ^ 16));
    bf16x8 ah, al;
    cvt8(va, vb, ah, al);

    const int m   = fr & 7;
    const int bof = fr * 128 + ((((T & 1) * 4) + g) ^ m) * 16;   // bytes, hi plane
    const unsigned char* bh = lds + BH_OFF + bof;
    bf16x8 b0 = *reinterpret_cast<const bf16x8*>(bh);
    bf16x8 b1 = *reinterpret_cast<const bf16x8*>(bh + 2048);
    bf16x8 b2 = *reinterpret_cast<const bf16x8*>(bh + 4096);
    bf16x8 b3 = *reinterpret_cast<const bf16x8*>(bh + 6144);
    acc[0] = MFMA_B16(ah, b0, acc[0]);
    acc[1] = MFMA_B16(ah, b1, acc[1]);
    acc[2] = MFMA_B16(ah, b2, acc[2]);
    acc[3] = MFMA_B16(ah, b3, acc[3]);
    acc[0] = MFMA_B16(al, b0, acc[0]);
    acc[1] = MFMA_B16(al, b1, acc[1]);
    acc[2] = MFMA_B16(al, b2, acc[2]);
    acc[3] = MFMA_B16(al, b3, acc[3]);
    const unsigned char* blp = lds + BL_OFF + bof;
    b0 = *reinterpret_cast<const bf16x8*>(blp);
    b1 = *reinterpret_cast<const bf16x8*>(blp + 2048);
    b2 = *reinterpret_cast<const bf16x8*>(blp + 4096);
    b3 = *reinterpret_cast<const bf16x8*>(blp + 6144);
    acc[0] = MFMA_B16(ah, b0, acc[0]);
    acc[1] = MFMA_B16(ah, b1, acc[1]);
    acc[2] = MFMA_B16(ah, b2, acc[2]);
    acc[3] = MFMA_B16(ah, b3, acc[3]);

    if constexpr (T + 1 < 16)
        tiles<T + 1>(xsrc, xw, lds, ag, bvalid, brow, sl, va_off, fr, g, acc, bn0, bn1);
}

// LDS 48 KB: x = 8 waves x (2 x 2048) = 32 KB; B hi/lo = 16 KB.
// 3 blocks/CU = 24 waves/CU = 6 waves/SIMD; VGPR cap 85.
__global__ __launch_bounds__(NT, 6)
void lt_mfma11(const float* __restrict__ x, const float* __restrict__ A,
               float* __restrict__ out) {
    __shared__ __align__(16) unsigned char lds[49152];

    const int tid  = threadIdx.x;
    const int wave = tid >> 6;
    const int lane = tid & 63;
    const int fr   = lane & 15;
    const int g    = lane >> 4;
    const int r0   = blockIdx.x * BM;

    unsigned char* xw = lds + wave * 4096;   // wave-private x double buffer
    // x DMA source: row = r0 + wave*16 + j*8 + (lane>>3); k-slot pre-swizzled
    const float* xsrc = x + (size_t)(r0 + wave * 16 + (lane >> 3)) * KD
                          + (((lane & 7) ^ ((lane >> 3) & 7)) << 2);
    // B staging roles: 8 threads per row, 8 k each
    const int brow = tid >> 3;               // 0..63
    const int bq   = tid & 7;
    const int sl   = bq ^ (brow & 7);
    const bool bvalid = brow < NSPLIT;
    const float* ag = A + (size_t)brow * KD + bq * 8;
    // x frag byte offset: row fr, slot (2g)^(fr&7)
    const int va_off = (fr << 7) + (((2 * g) ^ (fr & 7)) << 4);

    f32x4 acc[4];
#pragma unroll
    for (int j = 0; j < 4; ++j) acc[j] = (f32x4)(0.f);

    // prologue: bn=chunk0 regs; x0 DMA; write chunk0 (waits bn only); bn=chunk1
    f32x4 bn0 = (f32x4)(0.f), bn1 = (f32x4)(0.f);
    if (bvalid) {
        bn0 = *reinterpret_cast<const f32x4*>(ag);
        bn1 = *reinterpret_cast<const f32x4*>(ag + 4);
    }
    gload_lds16(xsrc, xw);
    gload_lds16(xsrc + 8 * KD, xw + 1024);
    SCHED_FENCE();
    write_B(lds, brow, sl, bvalid, bn0, bn1);   // compiler vmcnt retires bn; x0 flies
    asm volatile("s_waitcnt lgkmcnt(0)" ::: "memory");
    __builtin_amdgcn_s_barrier();
    if (bvalid) {
        bn0 = *reinterpret_cast<const f32x4*>(ag + 64);
        bn1 = *reinterpret_cast<const f32x4*>(ag + 68);
    }
    SCHED_FENCE();

    tiles<0>(xsrc, xw, lds, ag, bvalid, brow, sl, va_off, fr, g, acc, bn0, bn1);

    // ---- epilogue: fully wave-private (own 4 KB x region), 4 sub-phases of 4 rows
    float* warea = reinterpret_cast<float*>(xw);      // [4][65]  = 1040 B
    float* zw    = warea + 260;                       // [4][127] = 2032 B (16B-aligned)
    const int o      = lane >> 4;                     // row 0..3
    const int part16 = lane & 15;                     // nodes [part16*8, +8)

#pragma unroll
    for (int s = 0; s < 4; ++s) {
        if (g == s) {                                 // rows s*4..s*4+3 live in g==s
#pragma unroll
            for (int nf = 0; nf < 4; ++nf)
#pragma unroll
                for (int rg = 0; rg < 4; ++rg)
                    warea[rg * 65 + nf * 16 + fr] = acc[nf][rg];
        }
        // same-wave LDS ordering via lgkmcnt; no barriers anywhere after K-loop
        const float* srow = warea + o * 65;
        float* zrow = zw + o * NNODES;
        if (part16 == 0) zrow[0] = 1.f;
        tree_walk16<0>(1.f, srow, zrow, part16);

        float* og = out + (size_t)(r0 + wave * 16 + s * 4) * NNODES;  // 16B-aligned
#pragma unroll
        for (int j = 0; j < 2; ++j) {
            const int idx = j * 64 + lane;
            if (idx < 127)
                *reinterpret_cast<f32x4*>(og + idx * 4) =
                    *reinterpret_cast<const f32x4*>(zw + idx * 4);
        }
    }
}

extern "C" void kernel_launch(void* const* d_in, const int* in_sizes, int n_in,
                              void* d_out, int out_size, void* d_ws, size_t ws_size,
                              hipStream_t stream) {
    const float* x = (const float*)d_in[0];   // [131072, 512]
    const float* A = (const float*)d_in[1];   // [63, 512]
    float* out = (float*)d_out;               // [131072, 127]
    const int nrows = in_sizes[0] / KD;       // 131072
    const int grid = nrows / BM;              // 1024 blocks; 768 resident, staggered
    lt_mfma11<<<dim3(grid), dim3(NT), 0, stream>>>(x, A, out);
}

// Round 13
// 92.061 us; speedup vs baseline: 1.0299x; 1.0299x over previous
//
#include <hip/hip_runtime.h>
#include <hip/hip_bf16.h>
#include <cstdint>

#define KD 512
#define BM 128
#define NT 512
#define NSPLIT 63
#define NNODES 127

typedef __attribute__((ext_vector_type(8))) short bf16x8;
typedef __attribute__((ext_vector_type(4))) float f32x4;

#define MFMA_B16(a, b, c) __builtin_amdgcn_mfma_f32_16x16x32_bf16(a, b, c, 0, 0, 0)
#define SCHED_FENCE() __builtin_amdgcn_sched_barrier(0)

static __device__ __forceinline__ unsigned short f2bf(float f) {
    return __builtin_bit_cast(unsigned short, __float2bfloat16(f));
}
static __device__ __forceinline__ float bf2f(unsigned short h) {
    return __builtin_bit_cast(float, (unsigned)h << 16);
}
static __device__ __forceinline__ unsigned pack2(float f0, float f1) {
    return (unsigned)f2bf(f0) | ((unsigned)f2bf(f1) << 16);
}

// 8 fp32 -> bf16 hi8 + residual lo8; named scalars only (stays in VGPRs)
static __device__ __forceinline__ void cvt8(f32x4 a, f32x4 b, bf16x8& hi, bf16x8& lo) {
    const unsigned short h0 = f2bf(a[0]), h1 = f2bf(a[1]), h2 = f2bf(a[2]), h3 = f2bf(a[3]);
    const unsigned short h4 = f2bf(b[0]), h5 = f2bf(b[1]), h6 = f2bf(b[2]), h7 = f2bf(b[3]);
    uint4 H = make_uint4((unsigned)h0 | ((unsigned)h1 << 16), (unsigned)h2 | ((unsigned)h3 << 16),
                         (unsigned)h4 | ((unsigned)h5 << 16), (unsigned)h6 | ((unsigned)h7 << 16));
    uint4 L = make_uint4(pack2(a[0] - bf2f(h0), a[1] - bf2f(h1)),
                         pack2(a[2] - bf2f(h2), a[3] - bf2f(h3)),
                         pack2(b[0] - bf2f(h4), b[1] - bf2f(h5)),
                         pack2(b[2] - bf2f(h6), b[3] - bf2f(h7)));
    hi = __builtin_bit_cast(bf16x8, H);
    lo = __builtin_bit_cast(bf16x8, L);
}

static __device__ __forceinline__ void gload_lds16(const void* g, void* l) {
    __builtin_amdgcn_global_load_lds(
        (const __attribute__((address_space(1))) unsigned int*)g,
        (__attribute__((address_space(3))) unsigned int*)l, 16, 0, 0);
}

template<int N> static __device__ __forceinline__ void vmwait() {
    if constexpr (N == 3)      asm volatile("s_waitcnt vmcnt(3)" ::: "memory");
    else if constexpr (N == 2) asm volatile("s_waitcnt vmcnt(2)" ::: "memory");
    else                       asm volatile("s_waitcnt vmcnt(0)" ::: "memory");
}

// DFS path-min; lane part16 stores clipped nodes [part16*8, part16*8+8)
template<int T>
static __device__ __forceinline__ void tree_walk16(float qt, const float* __restrict__ srow,
                                                   float* __restrict__ zrow, int part16) {
    const float s  = srow[T];
    const float ql = fminf(qt, s);
    const float qr = fminf(qt, -s);
    if (((2 * T + 1) >> 3) == part16) zrow[2 * T + 1] = fminf(fmaxf(ql, 0.f), 1.f);
    if (((2 * T + 2) >> 3) == part16) zrow[2 * T + 2] = fminf(fmaxf(qr, 0.f), 1.f);
    if constexpr (2 * T + 1 < NSPLIT) tree_walk16<2 * T + 1>(ql, srow, zrow, part16);
    if constexpr (2 * T + 2 < NSPLIT) tree_walk16<2 * T + 2>(qr, srow, zrow, part16);
}

// ---------------- prep: A -> bf16 hi/lo, chunk-contiguous & slot-swizzled for DMA.
// ws layout (ushort): chunk c (k=32c..32c+32) at c*4096: hi [64 rows][4 slots][8] then
// lo at +2048. slot' = ((k>>3)&3) ^ (row&3). 16 chunks x 8 KB = 128 KB.
__global__ __launch_bounds__(256)
void lt_prep(const float* __restrict__ A, unsigned short* __restrict__ ws) {
    const int gid = blockIdx.x * 256 + threadIdx.x;   // 4096 total
    const int r   = gid >> 6;                         // 0..63
    const int sk  = gid & 63;                         // 8-k group
    const int k   = sk << 3;
    f32x4 a = (f32x4)(0.f), b = (f32x4)(0.f);
    if (r < NSPLIT) {
        a = *reinterpret_cast<const f32x4*>(A + (size_t)r * KD + k);
        b = *reinterpret_cast<const f32x4*>(A + (size_t)r * KD + k + 4);
    }
    bf16x8 hi, lo;
    cvt8(a, b, hi, lo);
    const int chunk = sk >> 2;
    const int sl    = (sk & 3) ^ (r & 3);
    unsigned short* p = ws + chunk * 4096 + r * 32 + sl * 8;
    *reinterpret_cast<bf16x8*>(p)        = hi;
    *reinterpret_cast<bf16x8*>(p + 2048) = lo;
}

// ---------------- one 32-k tile. x: global->reg depth-3 rotating named slots.
// B: 1 gload_lds/wave/tile into 3-deep LDS ring. One raw s_barrier per tile,
// preceded by counted vmwait(3) (retires B_{T+1}+x_{T+1}; keeps tile-T issues).
template<int T>
static __device__ __forceinline__ void tiles(
        const float* xsl, const unsigned short* bsl, unsigned char* lds, int woff,
        int bo, f32x4& v0a, f32x4& v0b, f32x4& v1a, f32x4& v1b,
        f32x4& v2a, f32x4& v2b, f32x4 (&acc)[4]) {
    // issue tile T+2's loads first (B DMA + x regs, slot (T+2)%3 != T%3)
    if constexpr (T + 2 < 16) {
        gload_lds16(bsl + (T + 2) * 4096, lds + ((T + 2) % 3) * 8192 + woff);
        constexpr int S = (T + 2) % 3;
        f32x4& na = (S == 0) ? v0a : (S == 1) ? v1a : v2a;
        f32x4& nb = (S == 0) ? v0b : (S == 1) ? v1b : v2b;
        na = *reinterpret_cast<const f32x4*>(xsl + (T + 2) * 32);
        nb = *reinterpret_cast<const f32x4*>(xsl + (T + 2) * 32 + 4);
    }
    // consume tile T (x_T retired by T-1's wait; B_T visible via T-1's barrier)
    constexpr int C = T % 3;
    const f32x4& ca = (C == 0) ? v0a : (C == 1) ? v1a : v2a;
    const f32x4& cb = (C == 0) ? v0b : (C == 1) ? v1b : v2b;
    bf16x8 ah, al;
    cvt8(ca, cb, ah, al);

    const unsigned char* bb = lds + C * 8192;
    bf16x8 b0 = *reinterpret_cast<const bf16x8*>(bb + bo);
    bf16x8 b1 = *reinterpret_cast<const bf16x8*>(bb + bo + 1024);
    bf16x8 b2 = *reinterpret_cast<const bf16x8*>(bb + bo + 2048);
    bf16x8 b3 = *reinterpret_cast<const bf16x8*>(bb + bo + 3072);
    acc[0] = MFMA_B16(ah, b0, acc[0]);
    acc[1] = MFMA_B16(ah, b1, acc[1]);
    acc[2] = MFMA_B16(ah, b2, acc[2]);
    acc[3] = MFMA_B16(ah, b3, acc[3]);
    acc[0] = MFMA_B16(al, b0, acc[0]);
    acc[1] = MFMA_B16(al, b1, acc[1]);
    acc[2] = MFMA_B16(al, b2, acc[2]);
    acc[3] = MFMA_B16(al, b3, acc[3]);
    b0 = *reinterpret_cast<const bf16x8*>(bb + 4096 + bo);          // lo plane
    b1 = *reinterpret_cast<const bf16x8*>(bb + 4096 + bo + 1024);
    b2 = *reinterpret_cast<const bf16x8*>(bb + 4096 + bo + 2048);
    b3 = *reinterpret_cast<const bf16x8*>(bb + 4096 + bo + 3072);
    acc[0] = MFMA_B16(ah, b0, acc[0]);
    acc[1] = MFMA_B16(ah, b1, acc[1]);
    acc[2] = MFMA_B16(ah, b2, acc[2]);
    acc[3] = MFMA_B16(ah, b3, acc[3]);

    // counted wait + barrier (hand-traced: T<=13 -> 3; T==14 -> 0; T==15 -> none)
    if constexpr (T < 15) {
        SCHED_FENCE();
        vmwait<(T <= 13) ? 3 : 0>();
        SCHED_FENCE();
        __builtin_amdgcn_s_barrier();
        SCHED_FENCE();
        tiles<T + 1>(xsl, bsl, lds, woff, bo,
                     v0a, v0b, v1a, v1b, v2a, v2b, acc);
    }
}

// LDS 24 KB (3 x 8 KB B ring). Occupancy VGPR-bound: cap 85 -> 6 waves/SIMD.
__global__ __launch_bounds__(NT, 6)
void lt_mfma12(const float* __restrict__ x, const unsigned short* __restrict__ ws,
               float* __restrict__ out) {
    __shared__ __align__(16) unsigned char lds[24576];

    const int tid  = threadIdx.x;
    const int wave = tid >> 6;
    const int lane = tid & 63;
    const int fr   = lane & 15;
    const int g    = lane >> 4;
    const int r0   = blockIdx.x * BM;

    // x per-lane source: row r0 + wave*16 + fr, k base g*8 (two f32x4 per tile)
    const float* xsl = x + (size_t)(r0 + wave * 16 + fr) * KD + g * 8;
    // B DMA per-lane source (1 KB/wave/chunk, linear) and uniform LDS dest offset
    const unsigned short* bsl = ws + wave * 512 + lane * 8;
    const int woff = wave * 1024;
    // B frag byte offset: row nf*16+fr (stride 64B), slot (g ^ (fr&3))
    const int bo = fr * 64 + ((g ^ (fr & 3)) << 4);

    f32x4 acc[4];
#pragma unroll
    for (int j = 0; j < 4; ++j) acc[j] = (f32x4)(0.f);
    f32x4 v0a = (f32x4)(0.f), v0b = v0a, v1a = v0a, v1b = v0a, v2a = v0a, v2b = v0a;

    // prologue: B0, B1 DMA; x0 -> slot0, x1 -> slot1. vmcnt(2) retires B0,B1,x0.
    gload_lds16(bsl, lds + woff);
    gload_lds16(bsl + 4096, lds + 8192 + woff);
    v0a = *reinterpret_cast<const f32x4*>(xsl);
    v0b = *reinterpret_cast<const f32x4*>(xsl + 4);
    v1a = *reinterpret_cast<const f32x4*>(xsl + 32);
    v1b = *reinterpret_cast<const f32x4*>(xsl + 36);
    SCHED_FENCE();
    vmwait<2>();
    SCHED_FENCE();
    __builtin_amdgcn_s_barrier();
    SCHED_FENCE();

    tiles<0>(xsl, bsl, lds, woff, bo, v0a, v0b, v1a, v1b, v2a, v2b, acc);

    __syncthreads();   // all B reads done; ring free for epilogue

    // ---- epilogue: wave-private 3 KB = warea[4][65] (1040B) + zw[4][127] (2032B)
    float* warea = reinterpret_cast<float*>(lds + wave * 3072);
    float* zw    = warea + 260;
    const int o      = lane >> 4;                     // row 0..3
    const int part16 = lane & 15;                     // nodes [part16*8, +8)

#pragma unroll
    for (int s = 0; s < 4; ++s) {
        if (g == s) {                                 // acc rows 4s..4s+3
#pragma unroll
            for (int nf = 0; nf < 4; ++nf)
#pragma unroll
                for (int rg = 0; rg < 4; ++rg)
                    warea[rg * 65 + nf * 16 + fr] = acc[nf][rg];
        }
        // same-wave LDS ordering (in-order DS per wave); no barriers
        const float* srow = warea + o * 65;
        float* zrow = zw + o * NNODES;
        if (part16 == 0) zrow[0] = 1.f;
        tree_walk16<0>(1.f, srow, zrow, part16);

        float* og = out + (size_t)(r0 + wave * 16 + s * 4) * NNODES;  // 2032B-aligned
#pragma unroll
        for (int j = 0; j < 2; ++j) {
            const int idx = j * 64 + lane;
            if (idx < 127)
                *reinterpret_cast<f32x4*>(og + idx * 4) =
                    *reinterpret_cast<const f32x4*>(zw + idx * 4);
        }
    }
}

extern "C" void kernel_launch(void* const* d_in, const int* in_sizes, int n_in,
                              void* d_out, int out_size, void* d_ws, size_t ws_size,
                              hipStream_t stream) {
    const float* x = (const float*)d_in[0];          // [131072, 512]
    const float* A = (const float*)d_in[1];          // [63, 512]
    float* out = (float*)d_out;                      // [131072, 127]
    unsigned short* ws = (unsigned short*)d_ws;      // 128 KB: B chunks (prep'd)
    const int nrows = in_sizes[0] / KD;              // 131072
    lt_prep<<<dim3(16), dim3(256), 0, stream>>>(A, ws);
    lt_mfma12<<<dim3(nrows / BM), dim3(NT), 0, stream>>>(x, ws, out);
}